// Round 2
// baseline (443.704 us; speedup 1.0000x reference)
//
#include <hip/hip_runtime.h>
#include <hip/hip_bf16.h>

typedef unsigned short u16;
typedef unsigned int   u32;
typedef __attribute__((ext_vector_type(4))) float f32x4;
typedef __attribute__((ext_vector_type(4))) u32   u32x4;
typedef __attribute__((ext_vector_type(8))) short bf16x8;

#define HWPIX  9216      // 96*96
#define NPIX   73728     // 8*96*96
#define LN_EPS 1e-5f
#define ZSTR   264       // bf16 elems per LDS row (256 + 8 pad)
#define MPIX   32        // pixels per block

__device__ __forceinline__ u16 f2bf(float f){
  u32 u = __builtin_bit_cast(u32, f);
  u += 0x7fffu + ((u >> 16) & 1u);          // RTNE
  return (u16)(u >> 16);
}
__device__ __forceinline__ float lo2f(u32 w){ return __builtin_bit_cast(float, w << 16); }
__device__ __forceinline__ float hi2f(u32 w){ return __builtin_bit_cast(float, w & 0xffff0000u); }
__device__ __forceinline__ float bfu2f(u16 h){ return __builtin_bit_cast(float, (u32)h << 16); }
__device__ __forceinline__ float fsigmoid(float v){ return __fdividef(1.f, 1.f + __expf(-v)); }
__device__ __forceinline__ float fsilu(float v){ return __fdividef(v, 1.f + __expf(-v)); }

// ---------------- kernel 1: weight convert + transpose (fp32 [K][N] -> bf16 [N][K]) ----
__global__ __launch_bounds__(256) void wconv(const float* __restrict__ pk,
                                             const float* __restrict__ gk,
                                             u16* __restrict__ wtp,   // [256][1024]
                                             u16* __restrict__ wtg)   // [256][512]
{
  int idx = blockIdx.x * 256 + threadIdx.x;
  {
    int k = idx >> 8, n = idx & 255;
    wtp[n * 1024 + k] = f2bf(pk[idx]);
  }
  if (idx < 512 * 256) {
    int k = idx >> 8, n = idx & 255;
    wtg[n * 512 + k] = f2bf(gk[idx]);
  }
}

// ---------------- kernel 2: per-(b,h) partial sums of h_norm over w ----------------
__global__ __launch_bounds__(256) void ln_partial(const float* __restrict__ x,
                                                  const float* __restrict__ g,
                                                  const float* __restrict__ bt,
                                                  float* __restrict__ partial) // [768][256]
{
  const int bh = blockIdx.x;
  const int tid = threadIdx.x;
  const int wv = tid >> 6, lane = tid & 63;
  const float* xrow = x + (size_t)bh * 96 * 256;
  __shared__ float red[4][256];

  f32x4 gv = *(const f32x4*)(g  + lane * 4);
  f32x4 bv = *(const f32x4*)(bt + lane * 4);
  f32x4 acc = {0.f, 0.f, 0.f, 0.f};

  for (int w = wv; w < 96; w += 4) {
    f32x4 v = *(const f32x4*)(xrow + w * 256 + lane * 4);
    float s  = v[0] + v[1] + v[2] + v[3];
    float s2 = v[0]*v[0] + v[1]*v[1] + v[2]*v[2] + v[3]*v[3];
    #pragma unroll
    for (int m = 1; m < 64; m <<= 1) { s += __shfl_xor(s, m); s2 += __shfl_xor(s2, m); }
    float mu  = s * (1.f / 256.f);
    float var = s2 * (1.f / 256.f) - mu * mu;
    float rs  = rsqrtf(var + LN_EPS);
    #pragma unroll
    for (int j = 0; j < 4; ++j) acc[j] += (v[j] - mu) * rs * gv[j] + bv[j];
  }
  *(f32x4*)(&red[wv][lane * 4]) = acc;
  __syncthreads();
  float s = red[0][tid] + red[1][tid] + red[2][tid] + red[3][tid];
  partial[(size_t)bh * 256 + tid] = s;
}

// ---------------- kernel 3: reduce rows -> spatial mean [8][256] -------------------
__global__ __launch_bounds__(256) void ln_mean(const float* __restrict__ partial,
                                               float* __restrict__ mean)
{
  int b = blockIdx.x, c = threadIdx.x;
  float s = 0.f;
  for (int h = 0; h < 96; ++h) s += partial[((size_t)b * 96 + h) * 256 + c];
  mean[b * 256 + c] = s * (1.f / 9216.f);
}

// ---------------- kernel 4: fused main ---------------------------------------------
// 32 pixels/block, 512 threads (8 waves, 2x4 grid: wr row-tile, wc 64-col range).
// B-fragments read directly from global (L2-resident weights) with depth-1 prefetch.
// zctx eliminated: wedge = m[c]*zd[c+s] - m[c+s]*zd[c]; dot_arg = zd[c]*(zd[c+s]-m[c+s]).
__global__ __launch_bounds__(512, 4) void fused(
    const float* __restrict__ x,
    const float* __restrict__ lng, const float* __restrict__ lnb,
    const u16*  __restrict__ wtp, const u16* __restrict__ wtg,
    const float* __restrict__ pbias, const float* __restrict__ gbias,
    const float* __restrict__ gamma, const float* __restrict__ meang,
    float* __restrict__ out)
{
  __shared__ u16 zdet[MPIX * ZSTR];   // h_norm bf16
  __shared__ u16 afg [MPIX * ZSTR];   // A_comp during GEMM1, g_feat during GEMM2

  const int tid  = threadIdx.x;
  const long pix0 = (long)blockIdx.x * MPIX;
  const int b    = (int)(pix0 / HWPIX);        // 9216 % 32 == 0: tiles never cross batch

  const int wave = tid >> 6, lane = tid & 63;
  const int wr = wave & 1, wc = wave >> 1;     // 2x4 wave grid
  const int fr = lane & 15, kq = lane >> 4;
  const int kq8 = kq * 8;

  const u16* wpb = wtp + (size_t)(wc * 64 + fr) * 1024;
  const u16* wgb = wtg + (size_t)(wc * 64 + fr) * 512;

  auto ldB = [&](int t, u32x4& r0, u32x4& r1, u32x4& r2, u32x4& r3) {
    if (t < 32) {
      const u16* s0 = wpb + t * 32 + kq8;
      r0 = *(const u32x4*)(s0);
      r1 = *(const u32x4*)(s0 + 16384);
      r2 = *(const u32x4*)(s0 + 32768);
      r3 = *(const u32x4*)(s0 + 49152);
    } else {
      const u16* s0 = wgb + (t - 32) * 32 + kq8;
      r0 = *(const u32x4*)(s0);
      r1 = *(const u32x4*)(s0 + 8192);
      r2 = *(const u32x4*)(s0 + 16384);
      r3 = *(const u32x4*)(s0 + 24576);
    }
  };

  // issue first B loads before preproc so L2 latency hides under LN compute
  u32x4 bc0, bc1, bc2, bc3;
  ldB(0, bc0, bc1, bc2, bc3);

  // ---- preproc: LN, stage z_det as bf16 (16 ch / thread) ----
  const int p = tid >> 4, o = tid & 15;
  {
    const float* xp = x + (pix0 + p) * 256 + o * 16;
    f32x4 v[4];
    float s = 0.f, s2 = 0.f;
    #pragma unroll
    for (int i = 0; i < 4; ++i) {
      v[i] = *(const f32x4*)(xp + i * 4);
      #pragma unroll
      for (int j = 0; j < 4; ++j) { s += v[i][j]; s2 += v[i][j] * v[i][j]; }
    }
    s += __shfl_xor(s, 1); s2 += __shfl_xor(s2, 1);
    s += __shfl_xor(s, 2); s2 += __shfl_xor(s2, 2);
    s += __shfl_xor(s, 4); s2 += __shfl_xor(s2, 4);
    s += __shfl_xor(s, 8); s2 += __shfl_xor(s2, 8);
    float mu  = s * (1.f / 256.f);
    float var = s2 * (1.f / 256.f) - mu * mu;
    float rs  = rsqrtf(var + LN_EPS);

    const float* gp = lng + o * 16;
    const float* bp = lnb + o * 16;
    u16* zd = zdet + p * ZSTR + o * 16;
    u32 dw[8];
    #pragma unroll
    for (int i = 0; i < 4; ++i) {
      f32x4 gg = *(const f32x4*)(gp + i * 4);
      f32x4 bb = *(const f32x4*)(bp + i * 4);
      float h0 = (v[i][0] - mu) * rs * gg[0] + bb[0];
      float h1 = (v[i][1] - mu) * rs * gg[1] + bb[1];
      float h2 = (v[i][2] - mu) * rs * gg[2] + bb[2];
      float h3 = (v[i][3] - mu) * rs * gg[3] + bb[3];
      dw[2*i]   = (u32)f2bf(h0) | ((u32)f2bf(h1) << 16);
      dw[2*i+1] = (u32)f2bf(h2) | ((u32)f2bf(h3) << 16);
    }
    *(u32x4*)(zd)     = (u32x4){dw[0], dw[1], dw[2], dw[3]};
    *(u32x4*)(zd + 8) = (u32x4){dw[4], dw[5], dw[6], dw[7]};
    if (o == 0) *(u32*)(zdet + p * ZSTR + 256) = dw[0];   // wrap pad ch[256,257]=ch[0,1]
  }

  // per-thread mean window (18 values: ch o*16 .. o*16+17, wrapped)
  float mar[18];
  {
    const float* mp = meang + b * 256;
    #pragma unroll
    for (int i = 0; i < 4; ++i) {
      f32x4 t = *(const f32x4*)(mp + o * 16 + i * 4);
      mar[4*i] = t[0]; mar[4*i+1] = t[1]; mar[4*i+2] = t[2]; mar[4*i+3] = t[3];
    }
    mar[16] = mp[(o * 16 + 16) & 255];
    mar[17] = mp[(o * 16 + 17) & 255];
  }

  f32x4 acc[4];
  #pragma unroll
  for (int i = 0; i < 4; ++i) acc[i] = {0.f, 0.f, 0.f, 0.f};
  f32x4 gf[4];

  const u16* arow = afg  + (wr * 16 + fr) * ZSTR;
  const u16* zrow = zdet + (wr * 16 + fr) * ZSTR;

  // ---- GEMM1: g_feat_pre = feats @ Wp, K = 4 comps x 256 ----
  #pragma unroll
  for (int comp = 0; comp < 4; ++comp) {
    __syncthreads();                    // afg free (prev comp fully read)
    {   // build A_comp (16 ch / thread) from zdet + mean regs
      const int s = 1 + (comp >> 1);
      const bool isdot = (comp & 1) == 0;
      const u16* zd = zdet + p * ZSTR + o * 16;
      u16* ao = afg + p * ZSTR + o * 16;
      u32x4 da = *(const u32x4*)zd;
      u32x4 db = *(const u32x4*)(zd + 8);
      u32 dc = *(const u32*)(zd + 16);
      u32 w[9] = {da[0], da[1], da[2], da[3], db[0], db[1], db[2], db[3], dc};
      u32 ow[8];
      #pragma unroll
      for (int j = 0; j < 8; ++j) {
        float zd0 = lo2f(w[j]), zd1 = hi2f(w[j]);
        float zs0, zs1;
        if (s == 1) { zs0 = hi2f(w[j]);     zs1 = lo2f(w[j+1]); }
        else        { zs0 = lo2f(w[j+1]);   zs1 = hi2f(w[j+1]); }
        float ms0 = mar[2*j + s], ms1 = mar[2*j + 1 + s];
        float r0, r1;
        if (isdot) {
          r0 = fsilu(zd0 * (zs0 - ms0));
          r1 = fsilu(zd1 * (zs1 - ms1));
        } else {
          r0 = mar[2*j]     * zs0 - ms0 * zd0;
          r1 = mar[2*j + 1] * zs1 - ms1 * zd1;
        }
        ow[j] = (u32)f2bf(r0) | ((u32)f2bf(r1) << 16);
      }
      *(u32x4*)(ao)     = (u32x4){ow[0], ow[1], ow[2], ow[3]};
      *(u32x4*)(ao + 8) = (u32x4){ow[4], ow[5], ow[6], ow[7]};
    }
    __syncthreads();                    // afg ready
    #pragma unroll
    for (int kk = 0; kk < 8; ++kk) {
      const int t = comp * 8 + kk;
      u32x4 n0, n1, n2, n3;
      ldB(t + 1, n0, n1, n2, n3);       // t+1 <= 32: always valid (32 -> gate chunk 0)
      bf16x8 a = *(const bf16x8*)(arow + kk * 32 + kq8);
      acc[0] = __builtin_amdgcn_mfma_f32_16x16x32_bf16(a, __builtin_bit_cast(bf16x8, bc0), acc[0], 0, 0, 0);
      acc[1] = __builtin_amdgcn_mfma_f32_16x16x32_bf16(a, __builtin_bit_cast(bf16x8, bc1), acc[1], 0, 0, 0);
      acc[2] = __builtin_amdgcn_mfma_f32_16x16x32_bf16(a, __builtin_bit_cast(bf16x8, bc2), acc[2], 0, 0, 0);
      acc[3] = __builtin_amdgcn_mfma_f32_16x16x32_bf16(a, __builtin_bit_cast(bf16x8, bc3), acc[3], 0, 0, 0);
      bc0 = n0; bc1 = n1; bc2 = n2; bc3 = n3;
    }
  }

  // ---- epilogue 1: g_feat = acc + pbias -> regs + afg(bf16), reset acc ----
  __syncthreads();                      // GEMM1 reads of afg done
  #pragma unroll
  for (int nt = 0; nt < 4; ++nt) {
    int col = wc * 64 + nt * 16 + fr;
    float pb = pbias[col];
    #pragma unroll
    for (int rr = 0; rr < 4; ++rr) {
      int row = wr * 16 + kq * 4 + rr;
      float gv = acc[nt][rr] + pb;
      gf[nt][rr] = gv;
      afg[row * ZSTR + col] = f2bf(gv);
    }
    acc[nt] = {0.f, 0.f, 0.f, 0.f};
  }
  __syncthreads();                      // g_feat visible

  // ---- GEMM2: alpha_pre = [h_norm | g_feat] @ Wg, K = 512 ----
  #pragma unroll
  for (int kk = 0; kk < 16; ++kk) {
    const int t = 32 + kk;
    u32x4 n0, n1, n2, n3;
    if (t + 1 < 48) ldB(t + 1, n0, n1, n2, n3);
    const u16* ab = (kk < 8) ? zrow : arow;
    bf16x8 a = *(const bf16x8*)(ab + (kk & 7) * 32 + kq8);
    acc[0] = __builtin_amdgcn_mfma_f32_16x16x32_bf16(a, __builtin_bit_cast(bf16x8, bc0), acc[0], 0, 0, 0);
    acc[1] = __builtin_amdgcn_mfma_f32_16x16x32_bf16(a, __builtin_bit_cast(bf16x8, bc1), acc[1], 0, 0, 0);
    acc[2] = __builtin_amdgcn_mfma_f32_16x16x32_bf16(a, __builtin_bit_cast(bf16x8, bc2), acc[2], 0, 0, 0);
    acc[3] = __builtin_amdgcn_mfma_f32_16x16x32_bf16(a, __builtin_bit_cast(bf16x8, bc3), acc[3], 0, 0, 0);
    if (t + 1 < 48) { bc0 = n0; bc1 = n1; bc2 = n2; bc3 = n3; }
  }

  // ---- epilogue 2: alpha, silu, LayerScale, residual ----
  #pragma unroll
  for (int nt = 0; nt < 4; ++nt) {
    int col = wc * 64 + nt * 16 + fr;
    float gb = gbias[col];
    float gm = gamma[col];
    #pragma unroll
    for (int rr = 0; rr < 4; ++rr) {
      int row = wr * 16 + kq * 4 + rr;
      float al = fsigmoid(acc[nt][rr] + gb);
      float h  = bfu2f(zdet[row * ZSTR + col]);
      float hm = (fsilu(h) + al * gf[nt][rr]) * gm;
      long gi = (pix0 + row) * 256 + col;
      out[gi] = x[gi] + hm;
    }
  }
}

extern "C" void kernel_launch(void* const* d_in, const int* in_sizes, int n_in,
                              void* d_out, int out_size, void* d_ws, size_t ws_size,
                              hipStream_t stream) {
  const float* x     = (const float*)d_in[0];
  const float* lng   = (const float*)d_in[1];
  const float* lnb   = (const float*)d_in[2];
  const float* pk    = (const float*)d_in[3];
  const float* pbias = (const float*)d_in[4];
  const float* gk    = (const float*)d_in[5];
  const float* gbias = (const float*)d_in[6];
  const float* gamma = (const float*)d_in[7];
  float* out = (float*)d_out;

  char* ws = (char*)d_ws;
  u16*   wtp     = (u16*)ws;                       // 524288 B
  u16*   wtg     = (u16*)(ws + 524288);            // 262144 B
  float* partial = (float*)(ws + 786432);          // 786432 B
  float* meang   = (float*)(ws + 1572864);         // 8192 B

  wconv<<<1024, 256, 0, stream>>>(pk, gk, wtp, wtg);
  ln_partial<<<768, 256, 0, stream>>>(x, lng, lnb, partial);
  ln_mean<<<8, 256, 0, stream>>>(partial, meang);
  fused<<<NPIX / MPIX, 512, 0, stream>>>(x, lng, lnb, wtp, wtg,
                                         pbias, gbias, gamma, meang, out);
}

// Round 3
// 285.984 us; speedup vs baseline: 1.5515x; 1.5515x over previous
//
#include <hip/hip_runtime.h>
#include <hip/hip_bf16.h>

typedef unsigned short u16;
typedef unsigned int   u32;
typedef __attribute__((ext_vector_type(4))) float f32x4;
typedef __attribute__((ext_vector_type(4))) u32   u32x4;
typedef __attribute__((ext_vector_type(8))) short bf16x8;

#define HWPIX  9216      // 96*96
#define NPIX   73728     // 8*96*96
#define LN_EPS 1e-5f
#define ZSTR   264       // bf16 elems per LDS row (256 + 8 pad; 528B stride -> ~2-way banks)
#define MPIX   64        // pixels per block
#define NSTEP  48        // 32 K-chunks GEMM1 + 16 GEMM2 (32 K-elems each)

__device__ __forceinline__ u16 f2bf(float f){
  u32 u = __builtin_bit_cast(u32, f);
  u += 0x7fffu + ((u >> 16) & 1u);          // RTNE
  return (u16)(u >> 16);
}
__device__ __forceinline__ float lo2f(u32 w){ return __builtin_bit_cast(float, w << 16); }
__device__ __forceinline__ float hi2f(u32 w){ return __builtin_bit_cast(float, w & 0xffff0000u); }
__device__ __forceinline__ float bfu2f(u16 h){ return __builtin_bit_cast(float, (u32)h << 16); }
__device__ __forceinline__ float fsigmoid(float v){ return __fdividef(1.f, 1.f + __expf(-v)); }
__device__ __forceinline__ float fsilu(float v){ return __fdividef(v, 1.f + __expf(-v)); }

__device__ __forceinline__ void gld16(const u16* g, u16* l){
  __builtin_amdgcn_global_load_lds((const __attribute__((address_space(1))) void*)g,
                                   (__attribute__((address_space(3))) void*)l,
                                   16, 0, 0);
}

// ---------------- kernel 1: weight convert into staging-order swizzled layout ------
// wsw[t][S][0..7] (u16): chunk t (0..47), slot S (0..1023). Thread/lane slot S maps to
// B-row n = (S>>9)*128 + ((S>>6)&7)*16 + ((S>>2)&15), phys k-slot p = S&3,
// content k-quarter kq = p ^ ((((S>>2)&15)>>1)&3)  (XOR bank swizzle).
__global__ __launch_bounds__(256) void wconv(const float* __restrict__ pk,
                                             const float* __restrict__ gk,
                                             u16* __restrict__ wsw)
{
  int gid = blockIdx.x * 256 + threadIdx.x;   // 49152 total = 192 blocks
  int t = gid >> 10, S = gid & 1023;
  int q = (S >> 2) & 15, pp = S & 3, w8 = (S >> 6) & 7, r = S >> 9;
  int n  = r * 128 + w8 * 16 + q;
  int kq = pp ^ ((q >> 1) & 3);
  const float* W; int k0;
  if (t < 32) { W = pk; k0 = t * 32 + kq * 8; }
  else        { W = gk; k0 = (t - 32) * 32 + kq * 8; }
  u32 ow[4];
  #pragma unroll
  for (int e = 0; e < 4; ++e) {
    float f0 = W[(size_t)(k0 + 2*e)     * 256 + n];
    float f1 = W[(size_t)(k0 + 2*e + 1) * 256 + n];
    ow[e] = (u32)f2bf(f0) | ((u32)f2bf(f1) << 16);
  }
  *(u32x4*)(wsw + (size_t)gid * 8) = (u32x4){ow[0], ow[1], ow[2], ow[3]};
}

// ---------------- kernel 2: per-(b,h) partial sums of h_norm over w ----------------
__global__ __launch_bounds__(256) void ln_partial(const float* __restrict__ x,
                                                  const float* __restrict__ g,
                                                  const float* __restrict__ bt,
                                                  float* __restrict__ partial) // [768][256]
{
  const int bh = blockIdx.x;
  const int tid = threadIdx.x;
  const int wv = tid >> 6, lane = tid & 63;
  const float* xrow = x + (size_t)bh * 96 * 256;
  __shared__ float red[4][256];

  f32x4 gv = *(const f32x4*)(g  + lane * 4);
  f32x4 bv = *(const f32x4*)(bt + lane * 4);
  f32x4 acc = {0.f, 0.f, 0.f, 0.f};

  for (int w = wv; w < 96; w += 4) {
    f32x4 v = *(const f32x4*)(xrow + w * 256 + lane * 4);
    float s  = v[0] + v[1] + v[2] + v[3];
    float s2 = v[0]*v[0] + v[1]*v[1] + v[2]*v[2] + v[3]*v[3];
    #pragma unroll
    for (int m = 1; m < 64; m <<= 1) { s += __shfl_xor(s, m); s2 += __shfl_xor(s2, m); }
    float mu  = s * (1.f / 256.f);
    float var = s2 * (1.f / 256.f) - mu * mu;
    float rs  = rsqrtf(var + LN_EPS);
    #pragma unroll
    for (int j = 0; j < 4; ++j) acc[j] += (v[j] - mu) * rs * gv[j] + bv[j];
  }
  *(f32x4*)(&red[wv][lane * 4]) = acc;
  __syncthreads();
  float s = red[0][tid] + red[1][tid] + red[2][tid] + red[3][tid];
  partial[(size_t)bh * 256 + tid] = s;
}

// ---------------- kernel 3: reduce rows -> spatial mean [8][256] -------------------
__global__ __launch_bounds__(256) void ln_mean(const float* __restrict__ partial,
                                               float* __restrict__ mean)
{
  int b = blockIdx.x, c = threadIdx.x;
  float s = 0.f;
  for (int h = 0; h < 96; ++h) s += partial[((size_t)b * 96 + h) * 256 + c];
  mean[b * 256 + c] = s * (1.f / 9216.f);
}

// ---------------- kernel 4: fused main ---------------------------------------------
// 64 pixels/block, 512 threads (8 waves 2x4). B staged via global_load_lds into a
// triple-buffered 16KB ring, one raw s_barrier + counted vmcnt(2) per K-step.
__global__ __launch_bounds__(512, 1) void fused(
    const float* __restrict__ x,
    const float* __restrict__ lng, const float* __restrict__ lnb,
    const u16*  __restrict__ wsw,
    const float* __restrict__ pbias, const float* __restrict__ gbias,
    const float* __restrict__ gamma, const float* __restrict__ meang,
    float* __restrict__ out)
{
  __shared__ u16 zdet[MPIX * ZSTR];   // h_norm bf16                (33792 B)
  __shared__ u16 zctx[MPIX * ZSTR];   // h_norm - spatial_mean      (33792 B)
  __shared__ u16 afg [MPIX * ZSTR];   // A_comp / g_feat            (33792 B)
  __shared__ u16 Blds[3 * 8192];      // B ring: 3 x 16KB           (49152 B)

  const int tid  = threadIdx.x;
  const long pix0 = (long)blockIdx.x * MPIX;
  const int b    = (int)(pix0 / HWPIX);      // 9216 % 64 == 0: never crosses batch
  const int p    = tid >> 3, o = tid & 7;    // 8 lanes/pixel, 32 ch each

  // ---- preproc: LN + context centering, stage z_det/z_ctx as bf16 ----
  {
    const float* xp = x + (pix0 + p) * 256 + o * 32;
    f32x4 v[8];
    float s = 0.f, s2 = 0.f;
    #pragma unroll
    for (int i = 0; i < 8; ++i) {
      v[i] = *(const f32x4*)(xp + i * 4);
      #pragma unroll
      for (int j = 0; j < 4; ++j) { s += v[i][j]; s2 += v[i][j] * v[i][j]; }
    }
    s += __shfl_xor(s, 1); s2 += __shfl_xor(s2, 1);
    s += __shfl_xor(s, 2); s2 += __shfl_xor(s2, 2);
    s += __shfl_xor(s, 4); s2 += __shfl_xor(s2, 4);
    float mu  = s * (1.f / 256.f);
    float var = s2 * (1.f / 256.f) - mu * mu;
    float rs  = rsqrtf(var + LN_EPS);

    const float* gp = lng + o * 32;
    const float* bp = lnb + o * 32;
    const float* mp = meang + b * 256 + o * 32;
    u16* zd = zdet + p * ZSTR + o * 32;
    u16* zc = zctx + p * ZSTR + o * 32;
    u32 pad_d = 0, pad_c = 0;
    #pragma unroll
    for (int i = 0; i < 8; ++i) {
      f32x4 gg = *(const f32x4*)(gp + i * 4);
      f32x4 bb = *(const f32x4*)(bp + i * 4);
      f32x4 mm = *(const f32x4*)(mp + i * 4);
      float h0 = (v[i][0] - mu) * rs * gg[0] + bb[0];
      float h1 = (v[i][1] - mu) * rs * gg[1] + bb[1];
      float h2 = (v[i][2] - mu) * rs * gg[2] + bb[2];
      float h3 = (v[i][3] - mu) * rs * gg[3] + bb[3];
      u32 d0 = (u32)f2bf(h0) | ((u32)f2bf(h1) << 16);
      u32 d1 = (u32)f2bf(h2) | ((u32)f2bf(h3) << 16);
      u32 c0 = (u32)f2bf(h0 - mm[0]) | ((u32)f2bf(h1 - mm[1]) << 16);
      u32 c1 = (u32)f2bf(h2 - mm[2]) | ((u32)f2bf(h3 - mm[3]) << 16);
      *(u32*)(zd + i * 4)     = d0;
      *(u32*)(zd + i * 4 + 2) = d1;
      *(u32*)(zc + i * 4)     = c0;
      *(u32*)(zc + i * 4 + 2) = c1;
      if (i == 0) { pad_d = d0; pad_c = c0; }
    }
    if (o == 0) {      // wrap pad: ch [256,257] = ch [0,1] (max roll shift = 2)
      *(u32*)(zdet + p * ZSTR + 256) = pad_d;
      *(u32*)(zctx + p * ZSTR + 256) = pad_c;
    }
  }

  // ---- GEMM setup ----
  const int wave = tid >> 6, lane = tid & 63;
  const int wr = wave & 1, wc = wave >> 1;       // 2x4 wave grid
  const int fr = lane & 15, kq = lane >> 4;
  const int kq8 = kq * 8;

  float pb[4], gb[4], gm[4];
  #pragma unroll
  for (int nt = 0; nt < 4; ++nt) {
    int col = wc * 64 + nt * 16 + fr;
    pb[nt] = pbias[col]; gb[nt] = gbias[col]; gm[nt] = gamma[col];
  }

  f32x4 acc[2][4];
  f32x4 gf [2][4];
  #pragma unroll
  for (int i = 0; i < 2; ++i)
    #pragma unroll
    for (int j = 0; j < 4; ++j) acc[i][j] = (f32x4){0.f, 0.f, 0.f, 0.f};

  auto abuild = [&](int comp) {      // feats for component comp -> afg
    const int s = 1 + (comp >> 1);
    const bool isdot = (comp & 1) == 0;
    const u16* zd = zdet + p * ZSTR + o * 32;
    const u16* zc = zctx + p * ZSTR + o * 32;
    u16* ao = afg + p * ZSTR + o * 32;
    u32x4 da = *(const u32x4*)zd;
    u32x4 ca = *(const u32x4*)zc;
    #pragma unroll
    for (int gi = 0; gi < 4; ++gi) {
      u32x4 db = *(const u32x4*)(zd + gi * 8 + 8);
      u32x4 cb = *(const u32x4*)(zc + gi * 8 + 8);
      u32x4 dsh, csh;
      if (s == 1) {
        dsh[0]=(da[0]>>16)|(da[1]<<16); dsh[1]=(da[1]>>16)|(da[2]<<16);
        dsh[2]=(da[2]>>16)|(da[3]<<16); dsh[3]=(da[3]>>16)|(db[0]<<16);
        csh[0]=(ca[0]>>16)|(ca[1]<<16); csh[1]=(ca[1]>>16)|(ca[2]<<16);
        csh[2]=(ca[2]>>16)|(ca[3]<<16); csh[3]=(ca[3]>>16)|(cb[0]<<16);
      } else {
        dsh[0]=da[1]; dsh[1]=da[2]; dsh[2]=da[3]; dsh[3]=db[0];
        csh[0]=ca[1]; csh[1]=ca[2]; csh[2]=ca[3]; csh[3]=cb[0];
      }
      u32x4 ow;
      #pragma unroll
      for (int wd = 0; wd < 4; ++wd) {
        float zd0 = lo2f(da[wd]),  zd1 = hi2f(da[wd]);
        float zs0 = lo2f(csh[wd]), zs1 = hi2f(csh[wd]);
        float r0, r1;
        if (isdot) {
          r0 = fsilu(zd0 * zs0); r1 = fsilu(zd1 * zs1);
        } else {
          float zc0 = lo2f(ca[wd]),  zc1 = hi2f(ca[wd]);
          float ds0 = lo2f(dsh[wd]), ds1 = hi2f(dsh[wd]);
          r0 = zd0 * zs0 - zc0 * ds0;
          r1 = zd1 * zs1 - zc1 * ds1;
        }
        ow[wd] = (u32)f2bf(r0) | ((u32)f2bf(r1) << 16);
      }
      *(u32x4*)(ao + gi * 8) = ow;
      da = db; ca = cb;
    }
  };

  auto stage = [&](int t, int buf) {   // 2 x global_load_lds dwordx4 per thread
    const u16* src = wsw + (size_t)t * 8192 + tid * 8;
    u16* dst = Blds + buf * 8192 + (tid >> 6) * 512;   // wave-uniform; HW adds lane*16B
    gld16(src, dst);
    gld16(src + 4096, dst + 4096);
  };

  const int bswz = (kq ^ ((fr >> 1) & 3)) * 8;
  auto step = [&](int t, int buf) {
    const u16* ab = (t < 32) ? afg : ((t < 40) ? zdet : afg);
    const int ko = (t & 7) * 32 + kq8;
    bf16x8 a0 = *(const bf16x8*)(ab + (wr * 32 +      fr) * ZSTR + ko);
    bf16x8 a1 = *(const bf16x8*)(ab + (wr * 32 + 16 + fr) * ZSTR + ko);
    const u16* bb = Blds + buf * 8192 + wc * 2048 + fr * 32 + bswz;
    #pragma unroll
    for (int nt = 0; nt < 4; ++nt) {
      bf16x8 bv = *(const bf16x8*)(bb + nt * 512);
      acc[0][nt] = __builtin_amdgcn_mfma_f32_16x16x32_bf16(a0, bv, acc[0][nt], 0, 0, 0);
      acc[1][nt] = __builtin_amdgcn_mfma_f32_16x16x32_bf16(a1, bv, acc[1][nt], 0, 0, 0);
    }
  };

  __syncthreads();                    // zdet/zctx visible (one-time full drain)
  abuild(0);
  stage(0, 0);
  asm volatile("s_waitcnt lgkmcnt(0)" ::: "memory");
  __builtin_amdgcn_s_barrier();       // afg(comp0) visible; stage(0) in flight

  int cb = 0;
  for (int t = 0; t < NSTEP; ++t) {
    const int sb = (cb == 2) ? 0 : cb + 1;
    if (t < NSTEP - 1) {
      stage(t + 1, sb);
      asm volatile("s_waitcnt vmcnt(2)" ::: "memory");   // stage(t) landed; t+1 flying
    } else {
      asm volatile("s_waitcnt vmcnt(0)" ::: "memory");
    }
    __builtin_amdgcn_s_barrier();     // buf cb ready for everyone
    if (t == 8 || t == 16 || t == 24) {
      abuild(t >> 3);
      asm volatile("s_waitcnt lgkmcnt(0)" ::: "memory");
      __builtin_amdgcn_s_barrier();
    } else if (t == 32) {
      // epilogue 1: g_feat = acc + pbias -> regs + afg(bf16), reset acc
      #pragma unroll
      for (int mt = 0; mt < 2; ++mt)
        #pragma unroll
        for (int nt = 0; nt < 4; ++nt) {
          int col = wc * 64 + nt * 16 + fr;
          #pragma unroll
          for (int rr = 0; rr < 4; ++rr) {
            int row = wr * 32 + mt * 16 + kq * 4 + rr;
            float gv = acc[mt][nt][rr] + pb[nt];
            gf[mt][nt][rr] = gv;
            afg[row * ZSTR + col] = f2bf(gv);
          }
          acc[mt][nt] = (f32x4){0.f, 0.f, 0.f, 0.f};
        }
      asm volatile("s_waitcnt lgkmcnt(0)" ::: "memory");
      __builtin_amdgcn_s_barrier();
    }
    step(t, cb);
    cb = sb;
  }

  // ---- epilogue 2: alpha, silu, LayerScale, residual ----
  #pragma unroll
  for (int mt = 0; mt < 2; ++mt)
    #pragma unroll
    for (int nt = 0; nt < 4; ++nt) {
      int col = wc * 64 + nt * 16 + fr;
      #pragma unroll
      for (int rr = 0; rr < 4; ++rr) {
        int row = wr * 32 + mt * 16 + kq * 4 + rr;
        float al = fsigmoid(acc[mt][nt][rr] + gb[nt]);
        float h  = bfu2f(zdet[row * ZSTR + col]);
        float hm = (fsilu(h) + al * gf[mt][nt][rr]) * gm[nt];
        long gi = (pix0 + row) * 256 + col;
        out[gi] = x[gi] + hm;
      }
    }
}

extern "C" void kernel_launch(void* const* d_in, const int* in_sizes, int n_in,
                              void* d_out, int out_size, void* d_ws, size_t ws_size,
                              hipStream_t stream) {
  const float* x     = (const float*)d_in[0];
  const float* lng   = (const float*)d_in[1];
  const float* lnb   = (const float*)d_in[2];
  const float* pk    = (const float*)d_in[3];
  const float* pbias = (const float*)d_in[4];
  const float* gk    = (const float*)d_in[5];
  const float* gbias = (const float*)d_in[6];
  const float* gamma = (const float*)d_in[7];
  float* out = (float*)d_out;

  char* ws = (char*)d_ws;
  u16*   wsw     = (u16*)ws;                       // 48*8192*2 = 786432 B
  float* partial = (float*)(ws + 786432);          // 786432 B
  float* meang   = (float*)(ws + 1572864);         // 8192 B   (total 1581056 B)

  wconv<<<192, 256, 0, stream>>>(pk, gk, wsw);
  ln_partial<<<768, 256, 0, stream>>>(x, lng, lnb, partial);
  ln_mean<<<8, 256, 0, stream>>>(partial, meang);
  fused<<<NPIX / MPIX, 512, 0, stream>>>(x, lng, lnb, wsw,
                                         pbias, gbias, gamma, meang, out);
}